// Round 9
// baseline (146.339 us; speedup 1.0000x reference)
//
#include <hip/hip_runtime.h>
#include <hip/hip_bf16.h>
#include <stdint.h>

#define S_LEN 1024
#define BATCH 2
#define DM    768
#define NH    12
#define HD    64
#define W1    32
#define WIN   65
#define NQKV  2304
#define M_TOT 2048

typedef unsigned short u16;
typedef __attribute__((ext_vector_type(4))) float f4;
typedef __attribute__((ext_vector_type(4))) unsigned short us4;
typedef __attribute__((ext_vector_type(8))) unsigned short ushort8;
typedef __attribute__((ext_vector_type(8))) __bf16 bf16x8;
typedef __attribute__((ext_vector_type(4))) float f32x4;

__device__ inline float bf2f(u16 x) {
    union { unsigned u; float f; } z;
    z.u = ((unsigned)x) << 16;
    return z.f;
}
__device__ inline u16 f2bf(float x) {
    union { float f; unsigned u; } z;
    z.f = x;
    unsigned r = z.u + 0x7FFF + ((z.u >> 16) & 1);   // RNE
    return (u16)(r >> 16);
}

// ---------------------------------------------------------------------------
// Kernel 1: prep. Blocks [0,768): X f32 -> Xhi/Xlo bf16 split (block 0 also
// zeros pooled). Blocks [768,1200): transpose+concat+split weights ->
// Wt_hi/Wt_lo [n][k], n in [0,2304) over {Wq,Wk,Wv}.
// tile stride 69: (8*cg+jj)*69+rn -> bank (8cg+5jj+rn)%32, 2-way max (free).
// ---------------------------------------------------------------------------
__global__ __launch_bounds__(256) void prep(
    const float* __restrict__ X,
    const float* __restrict__ Wq, const float* __restrict__ Wk,
    const float* __restrict__ Wv,
    u16* __restrict__ Xhi, u16* __restrict__ Xlo,
    u16* __restrict__ Whi, u16* __restrict__ Wlo,
    float* __restrict__ pooled) {
    __shared__ float tile[64][69];
    const int t = threadIdx.x;
    const int bid = blockIdx.x;

    if (bid < 768) {
        if (bid == 0) {
            #pragma unroll
            for (int i = 0; i < 6; ++i) pooled[i * 256 + t] = 0.f;
        }
        const long base = (long)bid * 2048 + t * 8;
        f4 a = *(const f4*)&X[base];
        f4 b = *(const f4*)&X[base + 4];
        float v[8] = {a.x, a.y, a.z, a.w, b.x, b.y, b.z, b.w};
        ushort8 h, l;
        #pragma unroll
        for (int j = 0; j < 8; ++j) {
            u16 hb = f2bf(v[j]);
            h[j] = hb;
            l[j] = f2bf(v[j] - bf2f(hb));
        }
        *(ushort8*)&Xhi[base] = h;
        *(ushort8*)&Xlo[base] = l;
    } else {
        const int tw = bid - 768;           // 0..431
        const int n0 = (tw % 36) * 64;      // 0..2240
        const int k0 = (tw / 36) * 64;      // 0..704
        const int sel = n0 / DM;
        const int nl0 = n0 % DM;
        const float* W = (sel == 0) ? Wq : ((sel == 1) ? Wk : Wv);
        const int r = t >> 3;               // 0..31
        const int cg = t & 7;               // 0..7

        #pragma unroll
        for (int p = 0; p < 2; ++p) {
            int rr = r + p * 32;            // source row (k)
            long gb = (long)(k0 + rr) * DM + nl0 + cg * 8;
            *(f4*)&tile[rr][cg * 8]     = *(const f4*)&W[gb];
            *(f4*)&tile[rr][cg * 8 + 4] = *(const f4*)&W[gb + 4];
        }
        __syncthreads();
        #pragma unroll
        for (int p = 0; p < 2; ++p) {
            int rn = r + p * 32;            // output row (n)
            ushort8 h, l;
            #pragma unroll
            for (int jj = 0; jj < 8; ++jj) {
                float v = tile[cg * 8 + jj][rn];
                u16 hb = f2bf(v);
                h[jj] = hb;
                l[jj] = f2bf(v - bf2f(hb));
            }
            long ob = (long)(n0 + rn) * DM + k0 + cg * 8;
            *(ushort8*)&Whi[ob] = h;
            *(ushort8*)&Wlo[ob] = l;
        }
    }
}

// ---------------------------------------------------------------------------
// Kernel 2: fused QKV GEMM via split-bf16 MFMA.
// Q/K regions: 3-term (hh+hl+lh). V region (nt>=24): 1-term hh only —
// Vt is stored as plain bf16 so its rounding already dominates; skipping
// lo staging+MFMA halves LDS traffic for 1/3 of blocks.
// 128x64 tile (MxN), BK=64, 576 blocks, 2x4 XCD swizzle, XOR-swizzled LDS.
// Outputs: Qhi/Qlo/Khi/Klo bf16 [2048][768] (d-contig), Vt bf16 [b][h][d][s].
// ---------------------------------------------------------------------------
__global__ __launch_bounds__(256) void qkv_gemm_mfma(
    const u16* __restrict__ Xhi, const u16* __restrict__ Xlo,
    const u16* __restrict__ Whi, const u16* __restrict__ Wlo,
    const float* __restrict__ bq, const float* __restrict__ bk,
    const float* __restrict__ bv,
    u16* __restrict__ Qhi, u16* __restrict__ Qlo,
    u16* __restrict__ Khi, u16* __restrict__ Klo,
    u16* __restrict__ Vt) {
    __shared__ u16 As0[128 * 64];   // X hi: [row][8 chunks swizzled][8]
    __shared__ u16 As1[128 * 64];   // X lo
    __shared__ u16 Bs0[64 * 64];    // W hi
    __shared__ u16 Bs1[64 * 64];    // W lo

    const int bid = blockIdx.x;         // 0..575
    const int xcd = bid & 7;            // presumed XCD (RR dispatch)
    const int local = bid >> 3;         // 0..71 within XCD
    const int mt = (xcd & 1) * 8 + (local & 7);    // 0..15
    const int nt = (xcd >> 1) * 9 + (local >> 3);  // 0..35
    const int m0 = mt * 128;
    const int n0 = nt * 64;
    const bool vb = (nt >= 24);         // V region: 1-term path
    const int t = threadIdx.x;
    const int lane = t & 63;
    const int w = t >> 6;
    const int wm = w * 32;          // wave's M offset
    const int lrow = lane & 15;
    const int lq = lane >> 4;

    const f32x4 fzero = {0.f, 0.f, 0.f, 0.f};
    f32x4 acc[2][4];
    #pragma unroll
    for (int i = 0; i < 2; ++i)
        #pragma unroll
        for (int j = 0; j < 4; ++j) acc[i][j] = fzero;

    for (int kk = 0; kk < DM; kk += 64) {
        __syncthreads();
        // stage A (128 rows x 64 k)
        #pragma unroll
        for (int p = 0; p < 4; ++p) {
            int slot = p * 256 + t;         // 0..1023
            int row = slot >> 3;            // 0..127
            int skc = slot & 7;
            int sw = skc ^ (row & 7);
            long ga = (long)(m0 + row) * DM + kk + skc * 8;
            *(ushort8*)&As0[(row * 8 + sw) * 8] = *(const ushort8*)&Xhi[ga];
            if (!vb)
                *(ushort8*)&As1[(row * 8 + sw) * 8] = *(const ushort8*)&Xlo[ga];
        }
        // stage B (64 rows x 64 k)
        #pragma unroll
        for (int p = 0; p < 2; ++p) {
            int slot = p * 256 + t;         // 0..511
            int row = slot >> 3;            // 0..63
            int skc = slot & 7;
            int sw = skc ^ (row & 7);
            long gb = (long)(n0 + row) * DM + kk + skc * 8;
            *(ushort8*)&Bs0[(row * 8 + sw) * 8] = *(const ushort8*)&Whi[gb];
            if (!vb)
                *(ushort8*)&Bs1[(row * 8 + sw) * 8] = *(const ushort8*)&Wlo[gb];
        }
        __syncthreads();
        #pragma unroll
        for (int kh = 0; kh < 2; ++kh) {
            const int c = kh * 4 + lq;
            bf16x8 ah[2], bh[4];
            #pragma unroll
            for (int i = 0; i < 2; ++i) {
                int ar = wm + i * 16 + lrow;
                ah[i] = *(const bf16x8*)&As0[(ar * 8 + (c ^ (ar & 7))) * 8];
            }
            #pragma unroll
            for (int j = 0; j < 4; ++j) {
                int br = j * 16 + lrow;
                bh[j] = *(const bf16x8*)&Bs0[(br * 8 + (c ^ (br & 7))) * 8];
            }
            if (!vb) {
                bf16x8 al[2], bl[4];
                #pragma unroll
                for (int i = 0; i < 2; ++i) {
                    int ar = wm + i * 16 + lrow;
                    al[i] = *(const bf16x8*)&As1[(ar * 8 + (c ^ (ar & 7))) * 8];
                }
                #pragma unroll
                for (int j = 0; j < 4; ++j) {
                    int br = j * 16 + lrow;
                    bl[j] = *(const bf16x8*)&Bs1[(br * 8 + (c ^ (br & 7))) * 8];
                }
                #pragma unroll
                for (int i = 0; i < 2; ++i)
                    #pragma unroll
                    for (int j = 0; j < 4; ++j) {
                        acc[i][j] = __builtin_amdgcn_mfma_f32_16x16x32_bf16(
                            al[i], bh[j], acc[i][j], 0, 0, 0);
                        acc[i][j] = __builtin_amdgcn_mfma_f32_16x16x32_bf16(
                            ah[i], bl[j], acc[i][j], 0, 0, 0);
                        acc[i][j] = __builtin_amdgcn_mfma_f32_16x16x32_bf16(
                            ah[i], bh[j], acc[i][j], 0, 0, 0);
                    }
            } else {
                #pragma unroll
                for (int i = 0; i < 2; ++i)
                    #pragma unroll
                    for (int j = 0; j < 4; ++j)
                        acc[i][j] = __builtin_amdgcn_mfma_f32_16x16x32_bf16(
                            ah[i], bh[j], acc[i][j], 0, 0, 0);
            }
        }
    }

    const int region = n0 / DM;     // 0=Q, 1=K, 2=V
    const int nc0 = n0 % DM;
    const float* bias = (region == 0) ? bq : ((region == 1) ? bk : bv);

    if (region < 2) {
        u16* Hi = (region == 0) ? Qhi : Khi;
        u16* Lo = (region == 0) ? Qlo : Klo;
        #pragma unroll
        for (int j = 0; j < 4; ++j) {
            int col = nc0 + j * 16 + lrow;
            float bval = bias[col];
            #pragma unroll
            for (int i = 0; i < 2; ++i) {
                int row = m0 + wm + i * 16 + lq * 4;
                #pragma unroll
                for (int r = 0; r < 4; ++r) {
                    float v = acc[i][j][r] + bval;
                    u16 hb = f2bf(v);
                    long oi = (long)(row + r) * DM + col;
                    Hi[oi] = hb;
                    Lo[oi] = f2bf(v - bf2f(hb));
                }
            }
        }
    } else {
        // V: write transposed bf16 Vt[b][h][dloc][s]; n-tile = one head
        const int h = nc0 >> 6;
        #pragma unroll
        for (int j = 0; j < 4; ++j) {
            int dloc = j * 16 + lrow;
            float bval = bias[nc0 + dloc];
            #pragma unroll
            for (int i = 0; i < 2; ++i) {
                int row = m0 + wm + i * 16 + lq * 4;   // global s (incl batch)
                int b = row >> 10, sl = row & 1023;
                us4 pk;
                #pragma unroll
                for (int r = 0; r < 4; ++r) pk[r] = f2bf(acc[i][j][r] + bval);
                *(us4*)&Vt[(((long)(b * NH + h) * 64 + dloc) << 10) + sl] = pk;
            }
        }
    }
}

// ---------------------------------------------------------------------------
// Kernel 3: MFMA flash attention + pooled sum.
// Block (b, h, 64 queries); wave w = 16-query tile. Scores: split-bf16 MFMA
// with Q/K fragments gathered directly from global (row-contiguous 64B).
// Softmax f32 in C-layout; P->LDS (A-layout); PV via MFMA with Vt staged LDS.
// ---------------------------------------------------------------------------
__global__ __launch_bounds__(256) void attn_pool_mfma(
    const u16* __restrict__ Qhi, const u16* __restrict__ Qlo,
    const u16* __restrict__ Khi, const u16* __restrict__ Klo,
    const u16* __restrict__ Vt, float* __restrict__ pooled) {
    __shared__ u16 vt[64][136];        // V^T window: [d][key 128 + pad]
    __shared__ u16 pl[4][16][136];     // per-wave P: [wave][query row][key]
    const int b = blockIdx.z, h = blockIdx.y;
    const int s0 = blockIdx.x * 64;
    const int t = threadIdx.x;
    const int k0 = s0 - 32;

    // stage V^T window (coalesced; clamp at sequence edges - masked later)
    const u16* vtg = Vt + ((size_t)(b * NH + h) * 64) * 1024;
    #pragma unroll
    for (int it = 0; it < 4; ++it) {
        int item = it * 256 + t;
        int d = item >> 4, kc = item & 15;
        int kbase = k0 + kc * 8;
        if (kbase >= 0 && kbase + 7 < S_LEN) {
            *(ushort8*)&vt[d][kc * 8] = *(const ushort8*)&vtg[d * 1024 + kbase];
        } else {
            #pragma unroll
            for (int j = 0; j < 8; ++j) {
                int kk = kbase + j;
                int kcl = kk < 0 ? 0 : (kk > S_LEN - 1 ? S_LEN - 1 : kk);
                vt[d][kc * 8 + j] = vtg[d * 1024 + kcl];
            }
        }
    }
    __syncthreads();

    const int w = t >> 6, lane = t & 63;
    const int cl = lane & 15, q = lane >> 4;

    // ---- scores: S = Q . K^T (split-bf16, 3 mfma per tile) ----
    const f32x4 fzero = {0.f, 0.f, 0.f, 0.f};
    f32x4 accS[8];
    #pragma unroll
    for (int n = 0; n < 8; ++n) accS[n] = fzero;

    const long qrow = (long)(b * S_LEN + s0 + w * 16 + cl);
    bf16x8 aqh[2], aql[2];
    #pragma unroll
    for (int ks = 0; ks < 2; ++ks) {
        long qa = qrow * DM + h * HD + ks * 32 + q * 8;
        aqh[ks] = *(const bf16x8*)&Qhi[qa];
        aql[ks] = *(const bf16x8*)&Qlo[qa];
    }
    #pragma unroll
    for (int n = 0; n < 8; ++n) {
        int key = k0 + n * 16 + cl;
        int kcl = key < 0 ? 0 : (key > S_LEN - 1 ? S_LEN - 1 : key);
        long ka = (long)(b * S_LEN + kcl) * DM + h * HD;
        #pragma unroll
        for (int ks = 0; ks < 2; ++ks) {
            bf16x8 bkh = *(const bf16x8*)&Khi[ka + ks * 32 + q * 8];
            bf16x8 bkl = *(const bf16x8*)&Klo[ka + ks * 32 + q * 8];
            accS[n] = __builtin_amdgcn_mfma_f32_16x16x32_bf16(aql[ks], bkh, accS[n], 0, 0, 0);
            accS[n] = __builtin_amdgcn_mfma_f32_16x16x32_bf16(aqh[ks], bkl, accS[n], 0, 0, 0);
            accS[n] = __builtin_amdgcn_mfma_f32_16x16x32_bf16(aqh[ks], bkh, accS[n], 0, 0, 0);
        }
    }

    // ---- softmax (unnormalized) in C-layout: col=cl(key), row=q*4+r ----
    float l4[4] = {0.f, 0.f, 0.f, 0.f};
    #pragma unroll
    for (int n = 0; n < 8; ++n) {
        int key = k0 + n * 16 + cl;
        #pragma unroll
        for (int r = 0; r < 4; ++r) {
            int s = s0 + w * 16 + q * 4 + r;
            bool valid = (key >= s - W1) && (key <= s + W1) && (key >= 0) && (key < S_LEN);
            float p = valid ? __expf(accS[n][r] * 0.125f) : 0.f;
            accS[n][r] = p;
            l4[r] += p;
        }
    }
    #pragma unroll
    for (int m = 1; m <= 8; m <<= 1)
        #pragma unroll
        for (int r = 0; r < 4; ++r) l4[r] += __shfl_xor(l4[r], m, 64);

    // ---- P -> LDS in A-layout ----
    #pragma unroll
    for (int n = 0; n < 8; ++n)
        #pragma unroll
        for (int r = 0; r < 4; ++r)
            pl[w][q * 4 + r][n * 16 + cl] = f2bf(accS[n][r]);

    // ---- O = P . V (MFMA over 4 key-chunks of 32) ----
    f32x4 accO[4];
    #pragma unroll
    for (int n = 0; n < 4; ++n) accO[n] = fzero;
    bf16x8 ap[4];
    #pragma unroll
    for (int ks = 0; ks < 4; ++ks)
        ap[ks] = *(const bf16x8*)&pl[w][cl][ks * 32 + q * 8];
    #pragma unroll
    for (int n = 0; n < 4; ++n)
        #pragma unroll
        for (int ks = 0; ks < 4; ++ks) {
            bf16x8 bv = *(const bf16x8*)&vt[n * 16 + cl][ks * 32 + q * 8];
            accO[n] = __builtin_amdgcn_mfma_f32_16x16x32_bf16(ap[ks], bv, accO[n], 0, 0, 0);
        }

    // ---- normalize rows, pool over queries, atomic into pooled ----
    float rcp4[4];
    #pragma unroll
    for (int r = 0; r < 4; ++r) rcp4[r] = 1.0f / l4[r];
    #pragma unroll
    for (int n = 0; n < 4; ++n) {
        float pp = 0.f;
        #pragma unroll
        for (int r = 0; r < 4; ++r) pp += accO[n][r] * rcp4[r];
        pp += __shfl_xor(pp, 16, 64);
        pp += __shfl_xor(pp, 32, 64);
        if (q == 0)
            atomicAdd(&pooled[b * DM + h * HD + n * 16 + cl], pp);
    }
}

// ---------------------------------------------------------------------------
// Kernel 4: out = relu(pooled/S @ Wfc + bfc) -> f32
// ---------------------------------------------------------------------------
__global__ __launch_bounds__(256) void fc_relu_f(
    const float* __restrict__ pooled, const float* __restrict__ Wfc,
    const float* __restrict__ bfc, float* __restrict__ out) {
    __shared__ float red[2][4][64];
    const int t = threadIdx.x;
    const int nb = blockIdx.x;          // 0..11
    const int nn = t & 63;
    const int dg = t >> 6;              // 0..3
    const int n = nb * 64 + nn;
    float s0 = 0.f, s1 = 0.f;
    for (int d = dg * 192; d < dg * 192 + 192; ++d) {
        float wv = Wfc[(long)d * DM + n];
        s0 += pooled[d] * wv;
        s1 += pooled[DM + d] * wv;
    }
    red[0][dg][nn] = s0;
    red[1][dg][nn] = s1;
    __syncthreads();
    if (t < 128) {
        int bb = t >> 6;
        int n2 = t & 63;
        float sum = red[bb][0][n2] + red[bb][1][n2] + red[bb][2][n2] + red[bb][3][n2];
        sum = sum * (1.0f / (float)S_LEN) + bfc[nb * 64 + n2];
        sum = sum > 0.f ? sum : 0.f;
        out[bb * DM + nb * 64 + n2] = sum;
    }
}

// ---------------------------------------------------------------------------
extern "C" void kernel_launch(void* const* d_in, const int* in_sizes, int n_in,
                              void* d_out, int out_size, void* d_ws, size_t ws_size,
                              hipStream_t stream) {
    const float* X   = (const float*)d_in[0];
    const float* Wq  = (const float*)d_in[1];
    const float* bq  = (const float*)d_in[2];
    const float* Wk  = (const float*)d_in[3];
    const float* bk  = (const float*)d_in[4];
    const float* Wv  = (const float*)d_in[5];
    const float* bv  = (const float*)d_in[6];
    const float* Wfc = (const float*)d_in[7];
    const float* bfc = (const float*)d_in[8];

    char* ws = (char*)d_ws;
    const size_t SZ_XB = (size_t)M_TOT * DM * 2;              // 3,145,728
    const size_t SZ_WB = (size_t)NQKV * DM * 2;               // 3,538,944
    u16* Xhi = (u16*)(ws);
    u16* Xlo = (u16*)(ws + SZ_XB);
    u16* Whi = (u16*)(ws + 2 * SZ_XB);
    u16* Wlo = (u16*)(ws + 2 * SZ_XB + SZ_WB);
    u16* Qhi = (u16*)(ws + 2 * SZ_XB + 2 * SZ_WB);
    u16* Qlo = (u16*)(ws + 3 * SZ_XB + 2 * SZ_WB);
    u16* Khi = (u16*)(ws + 4 * SZ_XB + 2 * SZ_WB);
    u16* Klo = (u16*)(ws + 5 * SZ_XB + 2 * SZ_WB);
    u16* Vt  = (u16*)(ws + 6 * SZ_XB + 2 * SZ_WB);
    float* pooled = (float*)(ws + 7 * SZ_XB + 2 * SZ_WB);

    prep<<<1200, 256, 0, stream>>>(X, Wq, Wk, Wv, Xhi, Xlo, Whi, Wlo, pooled);

    qkv_gemm_mfma<<<576, 256, 0, stream>>>(
        Xhi, Xlo, Whi, Wlo, bq, bk, bv,
        Qhi, Qlo, Khi, Klo, Vt);

    attn_pool_mfma<<<dim3(16, NH, BATCH), 256, 0, stream>>>(
        Qhi, Qlo, Khi, Klo, Vt, pooled);

    fc_relu_f<<<12, 256, 0, stream>>>(pooled, Wfc, bfc, (float*)d_out);
}

// Round 10
// 131.438 us; speedup vs baseline: 1.1134x; 1.1134x over previous
//
#include <hip/hip_runtime.h>
#include <hip/hip_bf16.h>
#include <stdint.h>

#define S_LEN 1024
#define BATCH 2
#define DM    768
#define NH    12
#define HD    64
#define W1    32
#define WIN   65
#define NQKV  2304
#define M_TOT 2048

typedef unsigned short u16;
typedef __attribute__((ext_vector_type(4))) float f4;
typedef __attribute__((ext_vector_type(4))) unsigned short us4;
typedef __attribute__((ext_vector_type(8))) unsigned short ushort8;
typedef __attribute__((ext_vector_type(8))) __bf16 bf16x8;
typedef __attribute__((ext_vector_type(4))) float f32x4;

__device__ inline float bf2f(u16 x) {
    union { unsigned u; float f; } z;
    z.u = ((unsigned)x) << 16;
    return z.f;
}
__device__ inline u16 f2bf(float x) {
    union { float f; unsigned u; } z;
    z.f = x;
    unsigned r = z.u + 0x7FFF + ((z.u >> 16) & 1);   // RNE
    return (u16)(r >> 16);
}

// ---------------------------------------------------------------------------
// Kernel 1: prep. Blocks [0,768): X f32 -> Xhi bf16 (block 0 also zeros
// pooled; Xlo no longer needed — GEMM uses 2-term split, W-side lo only).
// Blocks [768,1200): transpose+concat+split weights -> Wt_hi/Wt_lo [n][k].
// tile stride 69: bank 2-way max (free).
// ---------------------------------------------------------------------------
__global__ __launch_bounds__(256) void prep(
    const float* __restrict__ X,
    const float* __restrict__ Wq, const float* __restrict__ Wk,
    const float* __restrict__ Wv,
    u16* __restrict__ Xhi,
    u16* __restrict__ Whi, u16* __restrict__ Wlo,
    float* __restrict__ pooled) {
    __shared__ float tile[64][69];
    const int t = threadIdx.x;
    const int bid = blockIdx.x;

    if (bid < 768) {
        if (bid == 0) {
            #pragma unroll
            for (int i = 0; i < 6; ++i) pooled[i * 256 + t] = 0.f;
        }
        const long base = (long)bid * 2048 + t * 8;
        f4 a = *(const f4*)&X[base];
        f4 b = *(const f4*)&X[base + 4];
        float v[8] = {a.x, a.y, a.z, a.w, b.x, b.y, b.z, b.w};
        ushort8 h;
        #pragma unroll
        for (int j = 0; j < 8; ++j) h[j] = f2bf(v[j]);
        *(ushort8*)&Xhi[base] = h;
    } else {
        const int tw = bid - 768;           // 0..431
        const int n0 = (tw % 36) * 64;      // 0..2240
        const int k0 = (tw / 36) * 64;      // 0..704
        const int sel = n0 / DM;
        const int nl0 = n0 % DM;
        const float* W = (sel == 0) ? Wq : ((sel == 1) ? Wk : Wv);
        const int r = t >> 3;               // 0..31
        const int cg = t & 7;               // 0..7

        #pragma unroll
        for (int p = 0; p < 2; ++p) {
            int rr = r + p * 32;            // source row (k)
            long gb = (long)(k0 + rr) * DM + nl0 + cg * 8;
            *(f4*)&tile[rr][cg * 8]     = *(const f4*)&W[gb];
            *(f4*)&tile[rr][cg * 8 + 4] = *(const f4*)&W[gb + 4];
        }
        __syncthreads();
        #pragma unroll
        for (int p = 0; p < 2; ++p) {
            int rn = r + p * 32;            // output row (n)
            ushort8 h, l;
            #pragma unroll
            for (int jj = 0; jj < 8; ++jj) {
                float v = tile[cg * 8 + jj][rn];
                u16 hb = f2bf(v);
                h[jj] = hb;
                l[jj] = f2bf(v - bf2f(hb));
            }
            long ob = (long)(n0 + rn) * DM + k0 + cg * 8;
            *(ushort8*)&Whi[ob] = h;
            *(ushort8*)&Wlo[ob] = l;
        }
    }
}

// ---------------------------------------------------------------------------
// Kernel 2: fused QKV GEMM, uniform 2-term split-bf16 MFMA:
//   acc = ah*bl + ah*bh   (X-side lo dropped: ~2^-10 relative, within margin)
// 128x64 tile (MxN), BK=64, 576 blocks, 2x4 XCD swizzle, XOR-swizzled LDS.
// 32 KB LDS/block -> 4+ blocks/CU. Wave strip 32x64: 2x4 MFMA tiles.
// Outputs: Qhi/Qlo/Khi/Klo bf16 [2048][768] (d-contig), Vt bf16 [b][h][d][s].
// ---------------------------------------------------------------------------
__global__ __launch_bounds__(256) void qkv_gemm_mfma(
    const u16* __restrict__ Xhi,
    const u16* __restrict__ Whi, const u16* __restrict__ Wlo,
    const float* __restrict__ bq, const float* __restrict__ bk,
    const float* __restrict__ bv,
    u16* __restrict__ Qhi, u16* __restrict__ Qlo,
    u16* __restrict__ Khi, u16* __restrict__ Klo,
    u16* __restrict__ Vt) {
    __shared__ u16 As0[128 * 64];   // X hi: [row][8 chunks swizzled][8]
    __shared__ u16 Bs0[64 * 64];    // W hi
    __shared__ u16 Bs1[64 * 64];    // W lo

    const int bid = blockIdx.x;         // 0..575
    const int xcd = bid & 7;            // presumed XCD (RR dispatch)
    const int local = bid >> 3;         // 0..71 within XCD
    const int mt = (xcd & 1) * 8 + (local & 7);    // 0..15
    const int nt = (xcd >> 1) * 9 + (local >> 3);  // 0..35
    const int m0 = mt * 128;
    const int n0 = nt * 64;
    const int t = threadIdx.x;
    const int lane = t & 63;
    const int w = t >> 6;
    const int wm = w * 32;          // wave's M offset
    const int lrow = lane & 15;
    const int lq = lane >> 4;

    const f32x4 fzero = {0.f, 0.f, 0.f, 0.f};
    f32x4 acc[2][4];
    #pragma unroll
    for (int i = 0; i < 2; ++i)
        #pragma unroll
        for (int j = 0; j < 4; ++j) acc[i][j] = fzero;

    for (int kk = 0; kk < DM; kk += 64) {
        __syncthreads();
        // stage A-hi (128 rows x 64 k)
        #pragma unroll
        for (int p = 0; p < 4; ++p) {
            int slot = p * 256 + t;         // 0..1023
            int row = slot >> 3;            // 0..127
            int skc = slot & 7;
            int sw = skc ^ (row & 7);
            long ga = (long)(m0 + row) * DM + kk + skc * 8;
            *(ushort8*)&As0[(row * 8 + sw) * 8] = *(const ushort8*)&Xhi[ga];
        }
        // stage B hi+lo (64 rows x 64 k)
        #pragma unroll
        for (int p = 0; p < 2; ++p) {
            int slot = p * 256 + t;         // 0..511
            int row = slot >> 3;            // 0..63
            int skc = slot & 7;
            int sw = skc ^ (row & 7);
            long gb = (long)(n0 + row) * DM + kk + skc * 8;
            *(ushort8*)&Bs0[(row * 8 + sw) * 8] = *(const ushort8*)&Whi[gb];
            *(ushort8*)&Bs1[(row * 8 + sw) * 8] = *(const ushort8*)&Wlo[gb];
        }
        __syncthreads();
        #pragma unroll
        for (int kh = 0; kh < 2; ++kh) {
            const int c = kh * 4 + lq;
            bf16x8 ah[2], bh[4], bl[4];
            #pragma unroll
            for (int i = 0; i < 2; ++i) {
                int ar = wm + i * 16 + lrow;
                ah[i] = *(const bf16x8*)&As0[(ar * 8 + (c ^ (ar & 7))) * 8];
            }
            #pragma unroll
            for (int j = 0; j < 4; ++j) {
                int br = j * 16 + lrow;
                int off = (br * 8 + (c ^ (br & 7))) * 8;
                bh[j] = *(const bf16x8*)&Bs0[off];
                bl[j] = *(const bf16x8*)&Bs1[off];
            }
            #pragma unroll
            for (int i = 0; i < 2; ++i)
                #pragma unroll
                for (int j = 0; j < 4; ++j) {
                    acc[i][j] = __builtin_amdgcn_mfma_f32_16x16x32_bf16(
                        ah[i], bl[j], acc[i][j], 0, 0, 0);
                    acc[i][j] = __builtin_amdgcn_mfma_f32_16x16x32_bf16(
                        ah[i], bh[j], acc[i][j], 0, 0, 0);
                }
        }
    }

    const int region = n0 / DM;     // 0=Q, 1=K, 2=V
    const int nc0 = n0 % DM;
    const float* bias = (region == 0) ? bq : ((region == 1) ? bk : bv);

    if (region < 2) {
        u16* Hi = (region == 0) ? Qhi : Khi;
        u16* Lo = (region == 0) ? Qlo : Klo;
        #pragma unroll
        for (int j = 0; j < 4; ++j) {
            int col = nc0 + j * 16 + lrow;
            float bval = bias[col];
            #pragma unroll
            for (int i = 0; i < 2; ++i) {
                int row = m0 + wm + i * 16 + lq * 4;
                #pragma unroll
                for (int r = 0; r < 4; ++r) {
                    float v = acc[i][j][r] + bval;
                    u16 hb = f2bf(v);
                    long oi = (long)(row + r) * DM + col;
                    Hi[oi] = hb;
                    Lo[oi] = f2bf(v - bf2f(hb));
                }
            }
        }
    } else {
        // V: write transposed bf16 Vt[b][h][dloc][s]; n-tile = one head
        const int h = nc0 >> 6;
        #pragma unroll
        for (int j = 0; j < 4; ++j) {
            int dloc = j * 16 + lrow;
            float bval = bias[nc0 + dloc];
            #pragma unroll
            for (int i = 0; i < 2; ++i) {
                int row = m0 + wm + i * 16 + lq * 4;   // global s (incl batch)
                int b = row >> 10, sl = row & 1023;
                us4 pk;
                #pragma unroll
                for (int r = 0; r < 4; ++r) pk[r] = f2bf(acc[i][j][r] + bval);
                *(us4*)&Vt[(((long)(b * NH + h) * 64 + dloc) << 10) + sl] = pk;
            }
        }
    }
}

// ---------------------------------------------------------------------------
// Kernel 3: MFMA flash attention + pooled sum.
// Block (b, h, 64 queries); wave w = 16-query tile. Scores: split-bf16 MFMA
// with Q/K fragments gathered directly from global (row-contiguous 64B).
// Softmax f32 in C-layout; P->LDS (A-layout); PV via MFMA with Vt staged LDS.
// ---------------------------------------------------------------------------
__global__ __launch_bounds__(256) void attn_pool_mfma(
    const u16* __restrict__ Qhi, const u16* __restrict__ Qlo,
    const u16* __restrict__ Khi, const u16* __restrict__ Klo,
    const u16* __restrict__ Vt, float* __restrict__ pooled) {
    __shared__ u16 vt[64][136];        // V^T window: [d][key 128 + pad]
    __shared__ u16 pl[4][16][136];     // per-wave P: [wave][query row][key]
    const int b = blockIdx.z, h = blockIdx.y;
    const int s0 = blockIdx.x * 64;
    const int t = threadIdx.x;
    const int k0 = s0 - 32;

    // stage V^T window (coalesced; clamp at sequence edges - masked later)
    const u16* vtg = Vt + ((size_t)(b * NH + h) * 64) * 1024;
    #pragma unroll
    for (int it = 0; it < 4; ++it) {
        int item = it * 256 + t;
        int d = item >> 4, kc = item & 15;
        int kbase = k0 + kc * 8;
        if (kbase >= 0 && kbase + 7 < S_LEN) {
            *(ushort8*)&vt[d][kc * 8] = *(const ushort8*)&vtg[d * 1024 + kbase];
        } else {
            #pragma unroll
            for (int j = 0; j < 8; ++j) {
                int kk = kbase + j;
                int kcl = kk < 0 ? 0 : (kk > S_LEN - 1 ? S_LEN - 1 : kk);
                vt[d][kc * 8 + j] = vtg[d * 1024 + kcl];
            }
        }
    }
    __syncthreads();

    const int w = t >> 6, lane = t & 63;
    const int cl = lane & 15, q = lane >> 4;

    // ---- scores: S = Q . K^T (split-bf16, 3 mfma per tile) ----
    const f32x4 fzero = {0.f, 0.f, 0.f, 0.f};
    f32x4 accS[8];
    #pragma unroll
    for (int n = 0; n < 8; ++n) accS[n] = fzero;

    const long qrow = (long)(b * S_LEN + s0 + w * 16 + cl);
    bf16x8 aqh[2], aql[2];
    #pragma unroll
    for (int ks = 0; ks < 2; ++ks) {
        long qa = qrow * DM + h * HD + ks * 32 + q * 8;
        aqh[ks] = *(const bf16x8*)&Qhi[qa];
        aql[ks] = *(const bf16x8*)&Qlo[qa];
    }
    #pragma unroll
    for (int n = 0; n < 8; ++n) {
        int key = k0 + n * 16 + cl;
        int kcl = key < 0 ? 0 : (key > S_LEN - 1 ? S_LEN - 1 : key);
        long ka = (long)(b * S_LEN + kcl) * DM + h * HD;
        #pragma unroll
        for (int ks = 0; ks < 2; ++ks) {
            bf16x8 bkh = *(const bf16x8*)&Khi[ka + ks * 32 + q * 8];
            bf16x8 bkl = *(const bf16x8*)&Klo[ka + ks * 32 + q * 8];
            accS[n] = __builtin_amdgcn_mfma_f32_16x16x32_bf16(aql[ks], bkh, accS[n], 0, 0, 0);
            accS[n] = __builtin_amdgcn_mfma_f32_16x16x32_bf16(aqh[ks], bkl, accS[n], 0, 0, 0);
            accS[n] = __builtin_amdgcn_mfma_f32_16x16x32_bf16(aqh[ks], bkh, accS[n], 0, 0, 0);
        }
    }

    // ---- softmax (unnormalized) in C-layout: col=cl(key), row=q*4+r ----
    float l4[4] = {0.f, 0.f, 0.f, 0.f};
    #pragma unroll
    for (int n = 0; n < 8; ++n) {
        int key = k0 + n * 16 + cl;
        #pragma unroll
        for (int r = 0; r < 4; ++r) {
            int s = s0 + w * 16 + q * 4 + r;
            bool valid = (key >= s - W1) && (key <= s + W1) && (key >= 0) && (key < S_LEN);
            float p = valid ? __expf(accS[n][r] * 0.125f) : 0.f;
            accS[n][r] = p;
            l4[r] += p;
        }
    }
    #pragma unroll
    for (int m = 1; m <= 8; m <<= 1)
        #pragma unroll
        for (int r = 0; r < 4; ++r) l4[r] += __shfl_xor(l4[r], m, 64);

    // ---- P -> LDS in A-layout ----
    #pragma unroll
    for (int n = 0; n < 8; ++n)
        #pragma unroll
        for (int r = 0; r < 4; ++r)
            pl[w][q * 4 + r][n * 16 + cl] = f2bf(accS[n][r]);

    // ---- O = P . V (MFMA over 4 key-chunks of 32) ----
    f32x4 accO[4];
    #pragma unroll
    for (int n = 0; n < 4; ++n) accO[n] = fzero;
    bf16x8 ap[4];
    #pragma unroll
    for (int ks = 0; ks < 4; ++ks)
        ap[ks] = *(const bf16x8*)&pl[w][cl][ks * 32 + q * 8];
    #pragma unroll
    for (int n = 0; n < 4; ++n)
        #pragma unroll
        for (int ks = 0; ks < 4; ++ks) {
            bf16x8 bv = *(const bf16x8*)&vt[n * 16 + cl][ks * 32 + q * 8];
            accO[n] = __builtin_amdgcn_mfma_f32_16x16x32_bf16(ap[ks], bv, accO[n], 0, 0, 0);
        }

    // ---- normalize rows, pool over queries, atomic into pooled ----
    float rcp4[4];
    #pragma unroll
    for (int r = 0; r < 4; ++r) rcp4[r] = 1.0f / l4[r];
    #pragma unroll
    for (int n = 0; n < 4; ++n) {
        float pp = 0.f;
        #pragma unroll
        for (int r = 0; r < 4; ++r) pp += accO[n][r] * rcp4[r];
        pp += __shfl_xor(pp, 16, 64);
        pp += __shfl_xor(pp, 32, 64);
        if (q == 0)
            atomicAdd(&pooled[b * DM + h * HD + n * 16 + cl], pp);
    }
}

// ---------------------------------------------------------------------------
// Kernel 4: out = relu(pooled/S @ Wfc + bfc) -> f32
// ---------------------------------------------------------------------------
__global__ __launch_bounds__(256) void fc_relu_f(
    const float* __restrict__ pooled, const float* __restrict__ Wfc,
    const float* __restrict__ bfc, float* __restrict__ out) {
    __shared__ float red[2][4][64];
    const int t = threadIdx.x;
    const int nb = blockIdx.x;          // 0..11
    const int nn = t & 63;
    const int dg = t >> 6;              // 0..3
    const int n = nb * 64 + nn;
    float s0 = 0.f, s1 = 0.f;
    for (int d = dg * 192; d < dg * 192 + 192; ++d) {
        float wv = Wfc[(long)d * DM + n];
        s0 += pooled[d] * wv;
        s1 += pooled[DM + d] * wv;
    }
    red[0][dg][nn] = s0;
    red[1][dg][nn] = s1;
    __syncthreads();
    if (t < 128) {
        int bb = t >> 6;
        int n2 = t & 63;
        float sum = red[bb][0][n2] + red[bb][1][n2] + red[bb][2][n2] + red[bb][3][n2];
        sum = sum * (1.0f / (float)S_LEN) + bfc[nb * 64 + n2];
        sum = sum > 0.f ? sum : 0.f;
        out[bb * DM + nb * 64 + n2] = sum;
    }
}

// ---------------------------------------------------------------------------
extern "C" void kernel_launch(void* const* d_in, const int* in_sizes, int n_in,
                              void* d_out, int out_size, void* d_ws, size_t ws_size,
                              hipStream_t stream) {
    const float* X   = (const float*)d_in[0];
    const float* Wq  = (const float*)d_in[1];
    const float* bq  = (const float*)d_in[2];
    const float* Wk  = (const float*)d_in[3];
    const float* bk  = (const float*)d_in[4];
    const float* Wv  = (const float*)d_in[5];
    const float* bv  = (const float*)d_in[6];
    const float* Wfc = (const float*)d_in[7];
    const float* bfc = (const float*)d_in[8];

    char* ws = (char*)d_ws;
    const size_t SZ_XB = (size_t)M_TOT * DM * 2;              // 3,145,728
    const size_t SZ_WB = (size_t)NQKV * DM * 2;               // 3,538,944
    u16* Xhi = (u16*)(ws);
    u16* Whi = (u16*)(ws + SZ_XB);
    u16* Wlo = (u16*)(ws + SZ_XB + SZ_WB);
    u16* Qhi = (u16*)(ws + SZ_XB + 2 * SZ_WB);
    u16* Qlo = (u16*)(ws + 2 * SZ_XB + 2 * SZ_WB);
    u16* Khi = (u16*)(ws + 3 * SZ_XB + 2 * SZ_WB);
    u16* Klo = (u16*)(ws + 4 * SZ_XB + 2 * SZ_WB);
    u16* Vt  = (u16*)(ws + 5 * SZ_XB + 2 * SZ_WB);
    float* pooled = (float*)(ws + 6 * SZ_XB + 2 * SZ_WB);

    prep<<<1200, 256, 0, stream>>>(X, Wq, Wk, Wv, Xhi, Whi, Wlo, pooled);

    qkv_gemm_mfma<<<576, 256, 0, stream>>>(
        Xhi, Whi, Wlo, bq, bk, bv,
        Qhi, Qlo, Khi, Klo, Vt);

    attn_pool_mfma<<<dim3(16, NH, BATCH), 256, 0, stream>>>(
        Qhi, Qlo, Khi, Klo, Vt, pooled);

    fc_relu_f<<<12, 256, 0, stream>>>(pooled, Wfc, bfc, (float*)d_out);
}

// Round 11
// 120.170 us; speedup vs baseline: 1.2178x; 1.0938x over previous
//
#include <hip/hip_runtime.h>
#include <hip/hip_bf16.h>
#include <stdint.h>

#define S_LEN 1024
#define BATCH 2
#define DM    768
#define NH    12
#define HD    64
#define W1    32
#define WIN   65
#define NQKV  2304
#define M_TOT 2048

typedef unsigned short u16;
typedef __attribute__((ext_vector_type(4))) float f4;
typedef __attribute__((ext_vector_type(4))) unsigned short us4;
typedef __attribute__((ext_vector_type(8))) unsigned short ushort8;
typedef __attribute__((ext_vector_type(8))) __bf16 bf16x8;
typedef __attribute__((ext_vector_type(4))) float f32x4;

__device__ inline float bf2f(u16 x) {
    union { unsigned u; float f; } z;
    z.u = ((unsigned)x) << 16;
    return z.f;
}
__device__ inline u16 f2bf(float x) {
    union { float f; unsigned u; } z;
    z.f = x;
    unsigned r = z.u + 0x7FFF + ((z.u >> 16) & 1);   // RNE
    return (u16)(r >> 16);
}

// ---------------------------------------------------------------------------
// Kernel 1: prep. Blocks [0,768): X f32 -> Xb bf16 (block 0 also zeros
// pooled). Blocks [768,1200): transpose+concat weights -> Wt bf16 [n][k],
// n in [0,2304) over {Wq,Wk,Wv}. tile stride 69: 2-way bank max (free).
// Plain bf16 throughout: R5..R10 absmax is pinned by attention P/V
// quantization (1.2207e-4 invariant), score/GEMM precision is not binding —
// mean-pooling over 1024 queries averages score noise to <1e-5 at output.
// ---------------------------------------------------------------------------
__global__ __launch_bounds__(256) void prep(
    const float* __restrict__ X,
    const float* __restrict__ Wq, const float* __restrict__ Wk,
    const float* __restrict__ Wv,
    u16* __restrict__ Xb, u16* __restrict__ Wt,
    float* __restrict__ pooled) {
    __shared__ float tile[64][69];
    const int t = threadIdx.x;
    const int bid = blockIdx.x;

    if (bid < 768) {
        if (bid == 0) {
            #pragma unroll
            for (int i = 0; i < 6; ++i) pooled[i * 256 + t] = 0.f;
        }
        const long base = (long)bid * 2048 + t * 8;
        f4 a = *(const f4*)&X[base];
        f4 b = *(const f4*)&X[base + 4];
        float v[8] = {a.x, a.y, a.z, a.w, b.x, b.y, b.z, b.w};
        ushort8 h;
        #pragma unroll
        for (int j = 0; j < 8; ++j) h[j] = f2bf(v[j]);
        *(ushort8*)&Xb[base] = h;
    } else {
        const int tw = bid - 768;           // 0..431
        const int n0 = (tw % 36) * 64;      // 0..2240
        const int k0 = (tw / 36) * 64;      // 0..704
        const int sel = n0 / DM;
        const int nl0 = n0 % DM;
        const float* W = (sel == 0) ? Wq : ((sel == 1) ? Wk : Wv);
        const int r = t >> 3;               // 0..31
        const int cg = t & 7;               // 0..7

        #pragma unroll
        for (int p = 0; p < 2; ++p) {
            int rr = r + p * 32;            // source row (k)
            long gb = (long)(k0 + rr) * DM + nl0 + cg * 8;
            *(f4*)&tile[rr][cg * 8]     = *(const f4*)&W[gb];
            *(f4*)&tile[rr][cg * 8 + 4] = *(const f4*)&W[gb + 4];
        }
        __syncthreads();
        #pragma unroll
        for (int p = 0; p < 2; ++p) {
            int rn = r + p * 32;            // output row (n)
            ushort8 h;
            #pragma unroll
            for (int jj = 0; jj < 8; ++jj)
                h[jj] = f2bf(tile[cg * 8 + jj][rn]);
            *(ushort8*)&Wt[(long)(n0 + rn) * DM + k0 + cg * 8] = h;
        }
    }
}

// ---------------------------------------------------------------------------
// Kernel 2: fused QKV GEMM, plain bf16 MFMA (1-term).
// 128x64 tile (MxN), BK=64, 576 blocks, 2x4 XCD swizzle, XOR-swizzled LDS.
// 24 KB LDS/block. Wave strip 32x64: 2x4 MFMA tiles.
// Outputs: Q/K bf16 [2048][768] (d-contig), Vt bf16 [b][h][d][s].
// ---------------------------------------------------------------------------
__global__ __launch_bounds__(256) void qkv_gemm_mfma(
    const u16* __restrict__ Xb, const u16* __restrict__ Wt,
    const float* __restrict__ bq, const float* __restrict__ bk,
    const float* __restrict__ bv,
    u16* __restrict__ Q, u16* __restrict__ K, u16* __restrict__ Vt) {
    __shared__ u16 As[128 * 64];    // X: [row][8 chunks swizzled][8]
    __shared__ u16 Bs[64 * 64];     // W

    const int bid = blockIdx.x;         // 0..575
    const int xcd = bid & 7;            // presumed XCD (RR dispatch)
    const int local = bid >> 3;         // 0..71 within XCD
    const int mt = (xcd & 1) * 8 + (local & 7);    // 0..15
    const int nt = (xcd >> 1) * 9 + (local >> 3);  // 0..35
    const int m0 = mt * 128;
    const int n0 = nt * 64;
    const int t = threadIdx.x;
    const int lane = t & 63;
    const int w = t >> 6;
    const int wm = w * 32;          // wave's M offset
    const int lrow = lane & 15;
    const int lq = lane >> 4;

    const f32x4 fzero = {0.f, 0.f, 0.f, 0.f};
    f32x4 acc[2][4];
    #pragma unroll
    for (int i = 0; i < 2; ++i)
        #pragma unroll
        for (int j = 0; j < 4; ++j) acc[i][j] = fzero;

    for (int kk = 0; kk < DM; kk += 64) {
        __syncthreads();
        // stage A (128 rows x 64 k)
        #pragma unroll
        for (int p = 0; p < 4; ++p) {
            int slot = p * 256 + t;         // 0..1023
            int row = slot >> 3;            // 0..127
            int skc = slot & 7;
            int sw = skc ^ (row & 7);
            long ga = (long)(m0 + row) * DM + kk + skc * 8;
            *(ushort8*)&As[(row * 8 + sw) * 8] = *(const ushort8*)&Xb[ga];
        }
        // stage B (64 rows x 64 k)
        #pragma unroll
        for (int p = 0; p < 2; ++p) {
            int slot = p * 256 + t;         // 0..511
            int row = slot >> 3;            // 0..63
            int skc = slot & 7;
            int sw = skc ^ (row & 7);
            long gb = (long)(n0 + row) * DM + kk + skc * 8;
            *(ushort8*)&Bs[(row * 8 + sw) * 8] = *(const ushort8*)&Wt[gb];
        }
        __syncthreads();
        #pragma unroll
        for (int kh = 0; kh < 2; ++kh) {
            const int c = kh * 4 + lq;
            bf16x8 ah[2], bh[4];
            #pragma unroll
            for (int i = 0; i < 2; ++i) {
                int ar = wm + i * 16 + lrow;
                ah[i] = *(const bf16x8*)&As[(ar * 8 + (c ^ (ar & 7))) * 8];
            }
            #pragma unroll
            for (int j = 0; j < 4; ++j) {
                int br = j * 16 + lrow;
                bh[j] = *(const bf16x8*)&Bs[(br * 8 + (c ^ (br & 7))) * 8];
            }
            #pragma unroll
            for (int i = 0; i < 2; ++i)
                #pragma unroll
                for (int j = 0; j < 4; ++j)
                    acc[i][j] = __builtin_amdgcn_mfma_f32_16x16x32_bf16(
                        ah[i], bh[j], acc[i][j], 0, 0, 0);
        }
    }

    const int region = n0 / DM;     // 0=Q, 1=K, 2=V
    const int nc0 = n0 % DM;
    const float* bias = (region == 0) ? bq : ((region == 1) ? bk : bv);

    if (region < 2) {
        u16* Out = (region == 0) ? Q : K;
        #pragma unroll
        for (int j = 0; j < 4; ++j) {
            int col = nc0 + j * 16 + lrow;
            float bval = bias[col];
            #pragma unroll
            for (int i = 0; i < 2; ++i) {
                int row = m0 + wm + i * 16 + lq * 4;
                #pragma unroll
                for (int r = 0; r < 4; ++r)
                    Out[(long)(row + r) * DM + col] = f2bf(acc[i][j][r] + bval);
            }
        }
    } else {
        // V: write transposed bf16 Vt[b][h][dloc][s]; n-tile = one head
        const int h = nc0 >> 6;
        #pragma unroll
        for (int j = 0; j < 4; ++j) {
            int dloc = j * 16 + lrow;
            float bval = bias[nc0 + dloc];
            #pragma unroll
            for (int i = 0; i < 2; ++i) {
                int row = m0 + wm + i * 16 + lq * 4;   // global s (incl batch)
                int b = row >> 10, sl = row & 1023;
                us4 pk;
                #pragma unroll
                for (int r = 0; r < 4; ++r) pk[r] = f2bf(acc[i][j][r] + bval);
                *(us4*)&Vt[(((long)(b * NH + h) * 64 + dloc) << 10) + sl] = pk;
            }
        }
    }
}

// ---------------------------------------------------------------------------
// Kernel 3: MFMA flash attention + pooled sum (plain bf16 QK^T).
// Block (b, h, 64 queries); wave w = 16-query tile. Q/K fragments gathered
// directly from global (row-contiguous 64B). Softmax f32 in C-layout;
// P->LDS (A-layout); PV via MFMA with Vt staged LDS.
// ---------------------------------------------------------------------------
__global__ __launch_bounds__(256) void attn_pool_mfma(
    const u16* __restrict__ Q, const u16* __restrict__ K,
    const u16* __restrict__ Vt, float* __restrict__ pooled) {
    __shared__ u16 vt[64][136];        // V^T window: [d][key 128 + pad]
    __shared__ u16 pl[4][16][136];     // per-wave P: [wave][query row][key]
    const int b = blockIdx.z, h = blockIdx.y;
    const int s0 = blockIdx.x * 64;
    const int t = threadIdx.x;
    const int k0 = s0 - 32;

    // stage V^T window (coalesced; clamp at sequence edges - masked later)
    const u16* vtg = Vt + ((size_t)(b * NH + h) * 64) * 1024;
    #pragma unroll
    for (int it = 0; it < 4; ++it) {
        int item = it * 256 + t;
        int d = item >> 4, kc = item & 15;
        int kbase = k0 + kc * 8;
        if (kbase >= 0 && kbase + 7 < S_LEN) {
            *(ushort8*)&vt[d][kc * 8] = *(const ushort8*)&vtg[d * 1024 + kbase];
        } else {
            #pragma unroll
            for (int j = 0; j < 8; ++j) {
                int kk = kbase + j;
                int kcl = kk < 0 ? 0 : (kk > S_LEN - 1 ? S_LEN - 1 : kk);
                vt[d][kc * 8 + j] = vtg[d * 1024 + kcl];
            }
        }
    }
    __syncthreads();

    const int w = t >> 6, lane = t & 63;
    const int cl = lane & 15, q = lane >> 4;

    // ---- scores: S = Q . K^T ----
    const f32x4 fzero = {0.f, 0.f, 0.f, 0.f};
    f32x4 accS[8];
    #pragma unroll
    for (int n = 0; n < 8; ++n) accS[n] = fzero;

    const long qrow = (long)(b * S_LEN + s0 + w * 16 + cl);
    bf16x8 aq[2];
    #pragma unroll
    for (int ks = 0; ks < 2; ++ks)
        aq[ks] = *(const bf16x8*)&Q[qrow * DM + h * HD + ks * 32 + q * 8];
    #pragma unroll
    for (int n = 0; n < 8; ++n) {
        int key = k0 + n * 16 + cl;
        int kcl = key < 0 ? 0 : (key > S_LEN - 1 ? S_LEN - 1 : key);
        long ka = (long)(b * S_LEN + kcl) * DM + h * HD;
        #pragma unroll
        for (int ks = 0; ks < 2; ++ks) {
            bf16x8 bk = *(const bf16x8*)&K[ka + ks * 32 + q * 8];
            accS[n] = __builtin_amdgcn_mfma_f32_16x16x32_bf16(aq[ks], bk, accS[n], 0, 0, 0);
        }
    }

    // ---- softmax (unnormalized) in C-layout: col=cl(key), row=q*4+r ----
    float l4[4] = {0.f, 0.f, 0.f, 0.f};
    #pragma unroll
    for (int n = 0; n < 8; ++n) {
        int key = k0 + n * 16 + cl;
        #pragma unroll
        for (int r = 0; r < 4; ++r) {
            int s = s0 + w * 16 + q * 4 + r;
            bool valid = (key >= s - W1) && (key <= s + W1) && (key >= 0) && (key < S_LEN);
            float p = valid ? __expf(accS[n][r] * 0.125f) : 0.f;
            accS[n][r] = p;
            l4[r] += p;
        }
    }
    #pragma unroll
    for (int m = 1; m <= 8; m <<= 1)
        #pragma unroll
        for (int r = 0; r < 4; ++r) l4[r] += __shfl_xor(l4[r], m, 64);

    // ---- P -> LDS in A-layout ----
    #pragma unroll
    for (int n = 0; n < 8; ++n)
        #pragma unroll
        for (int r = 0; r < 4; ++r)
            pl[w][q * 4 + r][n * 16 + cl] = f2bf(accS[n][r]);

    // ---- O = P . V (MFMA over 4 key-chunks of 32) ----
    f32x4 accO[4];
    #pragma unroll
    for (int n = 0; n < 4; ++n) accO[n] = fzero;
    bf16x8 ap[4];
    #pragma unroll
    for (int ks = 0; ks < 4; ++ks)
        ap[ks] = *(const bf16x8*)&pl[w][cl][ks * 32 + q * 8];
    #pragma unroll
    for (int n = 0; n < 4; ++n)
        #pragma unroll
        for (int ks = 0; ks < 4; ++ks) {
            bf16x8 bv = *(const bf16x8*)&vt[n * 16 + cl][ks * 32 + q * 8];
            accO[n] = __builtin_amdgcn_mfma_f32_16x16x32_bf16(ap[ks], bv, accO[n], 0, 0, 0);
        }

    // ---- normalize rows, pool over queries, atomic into pooled ----
    float rcp4[4];
    #pragma unroll
    for (int r = 0; r < 4; ++r) rcp4[r] = 1.0f / l4[r];
    #pragma unroll
    for (int n = 0; n < 4; ++n) {
        float pp = 0.f;
        #pragma unroll
        for (int r = 0; r < 4; ++r) pp += accO[n][r] * rcp4[r];
        pp += __shfl_xor(pp, 16, 64);
        pp += __shfl_xor(pp, 32, 64);
        if (q == 0)
            atomicAdd(&pooled[b * DM + h * HD + n * 16 + cl], pp);
    }
}

// ---------------------------------------------------------------------------
// Kernel 4: out = relu(pooled/S @ Wfc + bfc) -> f32
// ---------------------------------------------------------------------------
__global__ __launch_bounds__(256) void fc_relu_f(
    const float* __restrict__ pooled, const float* __restrict__ Wfc,
    const float* __restrict__ bfc, float* __restrict__ out) {
    __shared__ float red[2][4][64];
    const int t = threadIdx.x;
    const int nb = blockIdx.x;          // 0..11
    const int nn = t & 63;
    const int dg = t >> 6;              // 0..3
    const int n = nb * 64 + nn;
    float s0 = 0.f, s1 = 0.f;
    for (int d = dg * 192; d < dg * 192 + 192; ++d) {
        float wv = Wfc[(long)d * DM + n];
        s0 += pooled[d] * wv;
        s1 += pooled[DM + d] * wv;
    }
    red[0][dg][nn] = s0;
    red[1][dg][nn] = s1;
    __syncthreads();
    if (t < 128) {
        int bb = t >> 6;
        int n2 = t & 63;
        float sum = red[bb][0][n2] + red[bb][1][n2] + red[bb][2][n2] + red[bb][3][n2];
        sum = sum * (1.0f / (float)S_LEN) + bfc[nb * 64 + n2];
        sum = sum > 0.f ? sum : 0.f;
        out[bb * DM + nb * 64 + n2] = sum;
    }
}

// ---------------------------------------------------------------------------
extern "C" void kernel_launch(void* const* d_in, const int* in_sizes, int n_in,
                              void* d_out, int out_size, void* d_ws, size_t ws_size,
                              hipStream_t stream) {
    const float* X   = (const float*)d_in[0];
    const float* Wq  = (const float*)d_in[1];
    const float* bq  = (const float*)d_in[2];
    const float* Wk  = (const float*)d_in[3];
    const float* bk  = (const float*)d_in[4];
    const float* Wv  = (const float*)d_in[5];
    const float* bv  = (const float*)d_in[6];
    const float* Wfc = (const float*)d_in[7];
    const float* bfc = (const float*)d_in[8];

    char* ws = (char*)d_ws;
    const size_t SZ_XB = (size_t)M_TOT * DM * 2;              // 3,145,728
    const size_t SZ_WB = (size_t)NQKV * DM * 2;               // 3,538,944
    u16* Xb = (u16*)(ws);
    u16* Wt = (u16*)(ws + SZ_XB);
    u16* Q  = (u16*)(ws + SZ_XB + SZ_WB);
    u16* K  = (u16*)(ws + 2 * SZ_XB + SZ_WB);
    u16* Vt = (u16*)(ws + 3 * SZ_XB + SZ_WB);
    float* pooled = (float*)(ws + 4 * SZ_XB + SZ_WB);

    prep<<<1200, 256, 0, stream>>>(X, Wq, Wk, Wv, Xb, Wt, pooled);

    qkv_gemm_mfma<<<576, 256, 0, stream>>>(
        Xb, Wt, bq, bk, bv, Q, K, Vt);

    attn_pool_mfma<<<dim3(16, NH, BATCH), 256, 0, stream>>>(
        Q, K, Vt, pooled);

    fc_relu_f<<<12, 256, 0, stream>>>(pooled, Wfc, bfc, (float*)d_out);
}

// Round 12
// 119.753 us; speedup vs baseline: 1.2220x; 1.0035x over previous
//
#include <hip/hip_runtime.h>
#include <hip/hip_bf16.h>
#include <stdint.h>

#define S_LEN 1024
#define BATCH 2
#define DM    768
#define NH    12
#define HD    64
#define W1    32
#define WIN   65
#define NQKV  2304
#define M_TOT 2048

typedef unsigned short u16;
typedef __attribute__((ext_vector_type(4))) float f4;
typedef __attribute__((ext_vector_type(4))) unsigned short us4;
typedef __attribute__((ext_vector_type(8))) unsigned short ushort8;
typedef __attribute__((ext_vector_type(8))) __bf16 bf16x8;
typedef __attribute__((ext_vector_type(4))) float f32x4;

__device__ inline float bf2f(u16 x) {
    union { unsigned u; float f; } z;
    z.u = ((unsigned)x) << 16;
    return z.f;
}
__device__ inline u16 f2bf(float x) {
    union { float f; unsigned u; } z;
    z.f = x;
    unsigned r = z.u + 0x7FFF + ((z.u >> 16) & 1);   // RNE
    return (u16)(r >> 16);
}

// ---------------------------------------------------------------------------
// Kernel 1: prep. Blocks [0,768): X f32 -> Xb bf16 (block 0 also zeros
// pooled). Blocks [768,1200): transpose+concat weights -> Wt bf16 [n][k].
// Plain bf16: R5..R11 absmax pinned at 1.2207e-4 by attention P/V
// quantization; GEMM/score precision not binding (mean-pool averages it out).
// ---------------------------------------------------------------------------
__global__ __launch_bounds__(256) void prep(
    const float* __restrict__ X,
    const float* __restrict__ Wq, const float* __restrict__ Wk,
    const float* __restrict__ Wv,
    u16* __restrict__ Xb, u16* __restrict__ Wt,
    float* __restrict__ pooled) {
    __shared__ float tile[64][69];
    const int t = threadIdx.x;
    const int bid = blockIdx.x;

    if (bid < 768) {
        if (bid == 0) {
            #pragma unroll
            for (int i = 0; i < 6; ++i) pooled[i * 256 + t] = 0.f;
        }
        const long base = (long)bid * 2048 + t * 8;
        f4 a = *(const f4*)&X[base];
        f4 b = *(const f4*)&X[base + 4];
        float v[8] = {a.x, a.y, a.z, a.w, b.x, b.y, b.z, b.w};
        ushort8 h;
        #pragma unroll
        for (int j = 0; j < 8; ++j) h[j] = f2bf(v[j]);
        *(ushort8*)&Xb[base] = h;
    } else {
        const int tw = bid - 768;           // 0..431
        const int n0 = (tw % 36) * 64;      // 0..2240
        const int k0 = (tw / 36) * 64;      // 0..704
        const int sel = n0 / DM;
        const int nl0 = n0 % DM;
        const float* W = (sel == 0) ? Wq : ((sel == 1) ? Wk : Wv);
        const int r = t >> 3;               // 0..31
        const int cg = t & 7;               // 0..7

        #pragma unroll
        for (int p = 0; p < 2; ++p) {
            int rr = r + p * 32;            // source row (k)
            long gb = (long)(k0 + rr) * DM + nl0 + cg * 8;
            *(f4*)&tile[rr][cg * 8]     = *(const f4*)&W[gb];
            *(f4*)&tile[rr][cg * 8 + 4] = *(const f4*)&W[gb + 4];
        }
        __syncthreads();
        #pragma unroll
        for (int p = 0; p < 2; ++p) {
            int rn = r + p * 32;            // output row (n)
            ushort8 h;
            #pragma unroll
            for (int jj = 0; jj < 8; ++jj)
                h[jj] = f2bf(tile[cg * 8 + jj][rn]);
            *(ushort8*)&Wt[(long)(n0 + rn) * DM + k0 + cg * 8] = h;
        }
    }
}

// ---------------------------------------------------------------------------
// Kernel 2: fused QKV GEMM, plain bf16 MFMA.
// 128x64 tile (MxN), BK=64, 576 blocks, 2x4 XCD swizzle, XOR-swizzled LDS.
// 24 KB LDS/block. Wave strip 32x64: 2x4 MFMA tiles.
// Outputs: Q/K bf16 [2048][768] (d-contig), Vt bf16 [b][h][d][s].
// ---------------------------------------------------------------------------
__global__ __launch_bounds__(256) void qkv_gemm_mfma(
    const u16* __restrict__ Xb, const u16* __restrict__ Wt,
    const float* __restrict__ bq, const float* __restrict__ bk,
    const float* __restrict__ bv,
    u16* __restrict__ Q, u16* __restrict__ K, u16* __restrict__ Vt) {
    __shared__ u16 As[128 * 64];    // X: [row][8 chunks swizzled][8]
    __shared__ u16 Bs[64 * 64];     // W

    const int bid = blockIdx.x;         // 0..575
    const int xcd = bid & 7;            // presumed XCD (RR dispatch)
    const int local = bid >> 3;         // 0..71 within XCD
    const int mt = (xcd & 1) * 8 + (local & 7);    // 0..15
    const int nt = (xcd >> 1) * 9 + (local >> 3);  // 0..35
    const int m0 = mt * 128;
    const int n0 = nt * 64;
    const int t = threadIdx.x;
    const int lane = t & 63;
    const int w = t >> 6;
    const int wm = w * 32;          // wave's M offset
    const int lrow = lane & 15;
    const int lq = lane >> 4;

    const f32x4 fzero = {0.f, 0.f, 0.f, 0.f};
    f32x4 acc[2][4];
    #pragma unroll
    for (int i = 0; i < 2; ++i)
        #pragma unroll
        for (int j = 0; j < 4; ++j) acc[i][j] = fzero;

    for (int kk = 0; kk < DM; kk += 64) {
        __syncthreads();
        // stage A (128 rows x 64 k)
        #pragma unroll
        for (int p = 0; p < 4; ++p) {
            int slot = p * 256 + t;         // 0..1023
            int row = slot >> 3;            // 0..127
            int skc = slot & 7;
            int sw = skc ^ (row & 7);
            long ga = (long)(m0 + row) * DM + kk + skc * 8;
            *(ushort8*)&As[(row * 8 + sw) * 8] = *(const ushort8*)&Xb[ga];
        }
        // stage B (64 rows x 64 k)
        #pragma unroll
        for (int p = 0; p < 2; ++p) {
            int slot = p * 256 + t;         // 0..511
            int row = slot >> 3;            // 0..63
            int skc = slot & 7;
            int sw = skc ^ (row & 7);
            long gb = (long)(n0 + row) * DM + kk + skc * 8;
            *(ushort8*)&Bs[(row * 8 + sw) * 8] = *(const ushort8*)&Wt[gb];
        }
        __syncthreads();
        #pragma unroll
        for (int kh = 0; kh < 2; ++kh) {
            const int c = kh * 4 + lq;
            bf16x8 ah[2], bh[4];
            #pragma unroll
            for (int i = 0; i < 2; ++i) {
                int ar = wm + i * 16 + lrow;
                ah[i] = *(const bf16x8*)&As[(ar * 8 + (c ^ (ar & 7))) * 8];
            }
            #pragma unroll
            for (int j = 0; j < 4; ++j) {
                int br = j * 16 + lrow;
                bh[j] = *(const bf16x8*)&Bs[(br * 8 + (c ^ (br & 7))) * 8];
            }
            #pragma unroll
            for (int i = 0; i < 2; ++i)
                #pragma unroll
                for (int j = 0; j < 4; ++j)
                    acc[i][j] = __builtin_amdgcn_mfma_f32_16x16x32_bf16(
                        ah[i], bh[j], acc[i][j], 0, 0, 0);
        }
    }

    const int region = n0 / DM;     // 0=Q, 1=K, 2=V
    const int nc0 = n0 % DM;
    const float* bias = (region == 0) ? bq : ((region == 1) ? bk : bv);

    if (region < 2) {
        u16* Out = (region == 0) ? Q : K;
        #pragma unroll
        for (int j = 0; j < 4; ++j) {
            int col = nc0 + j * 16 + lrow;
            float bval = bias[col];
            #pragma unroll
            for (int i = 0; i < 2; ++i) {
                int row = m0 + wm + i * 16 + lq * 4;
                #pragma unroll
                for (int r = 0; r < 4; ++r)
                    Out[(long)(row + r) * DM + col] = f2bf(acc[i][j][r] + bval);
            }
        }
    } else {
        // V: write transposed bf16 Vt[b][h][dloc][s]; n-tile = one head
        const int h = nc0 >> 6;
        #pragma unroll
        for (int j = 0; j < 4; ++j) {
            int dloc = j * 16 + lrow;
            float bval = bias[nc0 + dloc];
            #pragma unroll
            for (int i = 0; i < 2; ++i) {
                int row = m0 + wm + i * 16 + lq * 4;   // global s (incl batch)
                int b = row >> 10, sl = row & 1023;
                us4 pk;
                #pragma unroll
                for (int r = 0; r < 4; ++r) pk[r] = f2bf(acc[i][j][r] + bval);
                *(us4*)&Vt[(((long)(b * NH + h) * 64 + dloc) << 10) + sl] = pk;
            }
        }
    }
}

// ---------------------------------------------------------------------------
// Kernel 3: MFMA flash attention + pooled sum (plain bf16 QK^T).
// Block (b, h, 32 queries) = 128 threads (2 waves of 16 queries); 96-key
// window (vs 128 for 64-query blocks): score tiles/wave 8->6, PV 4->3.
// 768 blocks, ~20 KB LDS. Q/K fragments direct from global; softmax f32 in
// C-layout; P->LDS (A-layout); PV via MFMA with Vt staged in LDS.
// ---------------------------------------------------------------------------
__global__ __launch_bounds__(128) void attn_pool_mfma(
    const u16* __restrict__ Q, const u16* __restrict__ K,
    const u16* __restrict__ Vt, float* __restrict__ pooled) {
    __shared__ u16 vt[64][104];        // V^T window: [d][key 96 + pad 8]
    __shared__ u16 pl[2][16][104];     // per-wave P: [wave][query row][key]
    const int b = blockIdx.z, h = blockIdx.y;
    const int s0 = blockIdx.x * 32;
    const int t = threadIdx.x;
    const int k0 = s0 - 32;

    // stage V^T window: 64 d x 96 keys = 768 8-elem chunks, 6 iters x 128 thr
    const u16* vtg = Vt + ((size_t)(b * NH + h) * 64) * 1024;
    #pragma unroll
    for (int it = 0; it < 6; ++it) {
        int slot = it * 128 + t;        // 0..767
        int d = slot / 12, kc = slot % 12;
        int kbase = k0 + kc * 8;
        if (kbase >= 0 && kbase + 7 < S_LEN) {
            *(ushort8*)&vt[d][kc * 8] = *(const ushort8*)&vtg[d * 1024 + kbase];
        } else {
            #pragma unroll
            for (int j = 0; j < 8; ++j) {
                int kk = kbase + j;
                int kcl = kk < 0 ? 0 : (kk > S_LEN - 1 ? S_LEN - 1 : kk);
                vt[d][kc * 8 + j] = vtg[d * 1024 + kcl];
            }
        }
    }
    __syncthreads();

    const int w = t >> 6, lane = t & 63;
    const int cl = lane & 15, q = lane >> 4;

    // ---- scores: S = Q . K^T (6 key-tiles of 16) ----
    const f32x4 fzero = {0.f, 0.f, 0.f, 0.f};
    f32x4 accS[6];
    #pragma unroll
    for (int n = 0; n < 6; ++n) accS[n] = fzero;

    const long qrow = (long)(b * S_LEN + s0 + w * 16 + cl);
    bf16x8 aq[2];
    #pragma unroll
    for (int ks = 0; ks < 2; ++ks)
        aq[ks] = *(const bf16x8*)&Q[qrow * DM + h * HD + ks * 32 + q * 8];
    #pragma unroll
    for (int n = 0; n < 6; ++n) {
        int key = k0 + n * 16 + cl;
        int kcl = key < 0 ? 0 : (key > S_LEN - 1 ? S_LEN - 1 : key);
        long ka = (long)(b * S_LEN + kcl) * DM + h * HD;
        #pragma unroll
        for (int ks = 0; ks < 2; ++ks) {
            bf16x8 bk = *(const bf16x8*)&K[ka + ks * 32 + q * 8];
            accS[n] = __builtin_amdgcn_mfma_f32_16x16x32_bf16(aq[ks], bk, accS[n], 0, 0, 0);
        }
    }

    // ---- softmax (unnormalized) in C-layout: col=cl(key), row=q*4+r ----
    float l4[4] = {0.f, 0.f, 0.f, 0.f};
    #pragma unroll
    for (int n = 0; n < 6; ++n) {
        int key = k0 + n * 16 + cl;
        #pragma unroll
        for (int r = 0; r < 4; ++r) {
            int s = s0 + w * 16 + q * 4 + r;
            bool valid = (key >= s - W1) && (key <= s + W1) && (key >= 0) && (key < S_LEN);
            float p = valid ? __expf(accS[n][r] * 0.125f) : 0.f;
            accS[n][r] = p;
            l4[r] += p;
        }
    }
    #pragma unroll
    for (int m = 1; m <= 8; m <<= 1)
        #pragma unroll
        for (int r = 0; r < 4; ++r) l4[r] += __shfl_xor(l4[r], m, 64);

    // ---- P -> LDS in A-layout ----
    #pragma unroll
    for (int n = 0; n < 6; ++n)
        #pragma unroll
        for (int r = 0; r < 4; ++r)
            pl[w][q * 4 + r][n * 16 + cl] = f2bf(accS[n][r]);

    // ---- O = P . V (MFMA over 3 key-chunks of 32) ----
    f32x4 accO[4];
    #pragma unroll
    for (int n = 0; n < 4; ++n) accO[n] = fzero;
    bf16x8 ap[3];
    #pragma unroll
    for (int ks = 0; ks < 3; ++ks)
        ap[ks] = *(const bf16x8*)&pl[w][cl][ks * 32 + q * 8];
    #pragma unroll
    for (int n = 0; n < 4; ++n)
        #pragma unroll
        for (int ks = 0; ks < 3; ++ks) {
            bf16x8 bv = *(const bf16x8*)&vt[n * 16 + cl][ks * 32 + q * 8];
            accO[n] = __builtin_amdgcn_mfma_f32_16x16x32_bf16(ap[ks], bv, accO[n], 0, 0, 0);
        }

    // ---- normalize rows, pool over the wave's 16 queries, atomic add ----
    float rcp4[4];
    #pragma unroll
    for (int r = 0; r < 4; ++r) rcp4[r] = 1.0f / l4[r];
    #pragma unroll
    for (int n = 0; n < 4; ++n) {
        float pp = 0.f;
        #pragma unroll
        for (int r = 0; r < 4; ++r) pp += accO[n][r] * rcp4[r];
        pp += __shfl_xor(pp, 16, 64);
        pp += __shfl_xor(pp, 32, 64);
        if (q == 0)
            atomicAdd(&pooled[b * DM + h * HD + n * 16 + cl], pp);
    }
}

// ---------------------------------------------------------------------------
// Kernel 4: out = relu(pooled/S @ Wfc + bfc) -> f32. 24 blocks = (batch, col64).
// ---------------------------------------------------------------------------
__global__ __launch_bounds__(256) void fc_relu_f(
    const float* __restrict__ pooled, const float* __restrict__ Wfc,
    const float* __restrict__ bfc, float* __restrict__ out) {
    __shared__ float red[4][64];
    const int t = threadIdx.x;
    const int nb = blockIdx.x % 12;     // col tile
    const int bb = blockIdx.x / 12;     // batch
    const int nn = t & 63;
    const int dg = t >> 6;              // 0..3
    const int n = nb * 64 + nn;
    float s = 0.f;
    for (int d = dg * 192; d < dg * 192 + 192; ++d)
        s += pooled[bb * DM + d] * Wfc[(long)d * DM + n];
    red[dg][nn] = s;
    __syncthreads();
    if (t < 64) {
        float sum = red[0][t] + red[1][t] + red[2][t] + red[3][t];
        sum = sum * (1.0f / (float)S_LEN) + bfc[nb * 64 + t];
        sum = sum > 0.f ? sum : 0.f;
        out[bb * DM + nb * 64 + t] = sum;
    }
}

// ---------------------------------------------------------------------------
extern "C" void kernel_launch(void* const* d_in, const int* in_sizes, int n_in,
                              void* d_out, int out_size, void* d_ws, size_t ws_size,
                              hipStream_t stream) {
    const float* X   = (const float*)d_in[0];
    const float* Wq  = (const float*)d_in[1];
    const float* bq  = (const float*)d_in[2];
    const float* Wk  = (const float*)d_in[3];
    const float* bk  = (const float*)d_in[4];
    const float* Wv  = (const float*)d_in[5];
    const float* bv  = (const float*)d_in[6];
    const float* Wfc = (const float*)d_in[7];
    const float* bfc = (const float*)d_in[8];

    char* ws = (char*)d_ws;
    const size_t SZ_XB = (size_t)M_TOT * DM * 2;              // 3,145,728
    const size_t SZ_WB = (size_t)NQKV * DM * 2;               // 3,538,944
    u16* Xb = (u16*)(ws);
    u16* Wt = (u16*)(ws + SZ_XB);
    u16* Q  = (u16*)(ws + SZ_XB + SZ_WB);
    u16* K  = (u16*)(ws + 2 * SZ_XB + SZ_WB);
    u16* Vt = (u16*)(ws + 3 * SZ_XB + SZ_WB);
    float* pooled = (float*)(ws + 4 * SZ_XB + SZ_WB);

    prep<<<1200, 256, 0, stream>>>(X, Wq, Wk, Wv, Xb, Wt, pooled);

    qkv_gemm_mfma<<<576, 256, 0, stream>>>(
        Xb, Wt, bq, bk, bv, Q, K, Vt);

    attn_pool_mfma<<<dim3(32, NH, BATCH), 128, 0, stream>>>(
        Q, K, Vt, pooled);

    fc_relu_f<<<24, 256, 0, stream>>>(pooled, Wfc, bfc, (float*)d_out);
}